// Round 11
// baseline (45.476 us; speedup 1.0000x reference)
//
#include <hip/hip_runtime.h>
#include <hip/hip_fp16.h>
#include <math.h>

#define N_NODES 10000
#define N_EDGES 160000
#define TBL_N 63                // intervals; 64 rows -> 64*64*8B = 32 KiB LDS (4 blocks/CU, 32 waves/CU)
#define TBL_ROWS 64
#define ACT_C 1.676518f         // 1/sqrt(E[silu(z)^2]), z~N(0,1)
#define CAP 64                  // bucket capacity per node (mean valid degree ~15.4; P(>64)~e^-40)
#define S3 1.7320508075688772f

#define SCAT_BLOCKS 625         // 160000 edges / 256
#define CONV_BLOCKS 2500        // 4 nodes per block (wave-per-node)
#define TBL_BLOCKS  16          // 64 waves == 64 rows
#define GATHER_BLOCKS 1024      // 4 blocks/CU x 256 CU
#define GATHER_THREADS 512      // 8 waves; target 8 waves/SIMD occupancy

// mix table rows: lane u = half4 {mA,mB,mC,mD} for channels {u,64+u,128+u,192+u}
__device__ uint2  g_tbl[TBL_ROWS * 64];
// packed node features: lane u = half4 {m0, vx, vy, vz}
__device__ uint2  g_nd2[N_NODES * 64];
// counters: zero at module load (.bss); gather resets to zero at end of EVERY call
__device__ int    g_cnt[N_NODES];
// bucket record: {yhat_x, yhat_y, yhat_z, bits = sender<<16 | idx7<<9 | frac9}
__device__ float4 g_bkt[N_NODES * CAP];

__device__ __forceinline__ float2 h2f(unsigned int v) {
    __half2 h = *(__half2*)&v;
    return __half22float2(h);
}

// Fused prep+scatter: roles by blockIdx. No inter-role dependencies
// (scatter needs only g_cnt==0, guaranteed by previous gather / module load).
__global__ __launch_bounds__(256) void prep_scatter(
    const float* __restrict__ W1, const float* __restrict__ W2, const float* __restrict__ W3,
    const float* __restrict__ node_scalars, const float* __restrict__ node_vectors,
    const float* __restrict__ vectors, const int* __restrict__ senders,
    const int* __restrict__ receivers)
{
    const int bx = (int)blockIdx.x;
    const int tid = threadIdx.x;
    const int lane = tid & 63;
    const int wl = tid >> 6;

    if (bx < SCAT_BLOCKS) {                    // ---- scatter edges into receiver buckets ----
        int e = bx * 256 + tid;
        if (e < N_EDGES) {
            float vx = vectors[3 * e], vy = vectors[3 * e + 1], vz = vectors[3 * e + 2];
            float x2 = vx * vx + vy * vy + vz * vz;
            if (x2 < 1.0f) {                   // envelope==0 edges dropped
                float invx = rsqrtf(x2);
                float x = x2 * invx;
                float t = x * (float)TBL_N;    // t < 63 -> idx <= 62, rows i,i+1 <= 63
                int idx = (int)t;            if (idx > TBL_N - 1) idx = TBL_N - 1;
                int fr  = (int)((t - (float)idx) * 512.0f);  if (fr > 511) fr = 511;
                unsigned int bits = ((unsigned int)senders[e] << 16) |
                                    ((unsigned int)idx << 9) | (unsigned int)fr;
                int r = receivers[e];
                int slot = atomicAdd(&g_cnt[r], 1);
                if (slot < CAP)                // overflow clamp (never taken in practice)
                    g_bkt[(r << 6) + slot] =
                        make_float4(vx * invx, vy * invx, vz * invx, __uint_as_float(bits));
            }
        }
        return;
    }
    if (bx < SCAT_BLOCKS + CONV_BLOCKS) {      // ---- fp16 node-feature packing ----
        int n = (bx - SCAT_BLOCKS) * 4 + wl;   // exactly covers [0,10000)
        float m0 = node_scalars[n * 64 + lane];
        const float* p = node_vectors + n * 192 + 3 * lane;
        __half2 h01 = __floats2half2_rn(m0, p[0]);
        __half2 h23 = __floats2half2_rn(p[1], p[2]);
        uint2 r;
        r.x = *(unsigned int*)&h01;
        r.y = *(unsigned int*)&h23;
        g_nd2[n * 64 + lane] = r;
        return;
    }

    // ---- mix-table MLP: 16 blocks * 4 waves = 64 waves, one per row ----
    __shared__ float h[4][64];
    int wid = (bx - SCAT_BLOCKS - CONV_BLOCKS) * 4 + wl;          // 0..63 exactly
    const float x = (float)wid * (1.0f / (float)TBL_N);
    float x2 = x * x, x3 = x2 * x, x6 = x3 * x3;
    float env = (x < 1.0f) ? (1.0f - 28.0f * x6 + 48.0f * x6 * x - 21.0f * x6 * x2) : 0.0f;
    const float pi = 3.14159265358979f;
    float radial[8];
    #pragma unroll
    for (int k = 1; k <= 8; ++k) {
        float b = (x == 0.0f) ? ((float)k * pi) : (sinf(pi * (float)k * x) / x);
        radial[k - 1] = 1.41421356237f * b * env;
    }
    float acc = 0.0f;
    #pragma unroll
    for (int k = 0; k < 8; ++k) acc += radial[k] * W1[k * 64 + lane];
    acc *= 0.35355339059f;                     // 1/sqrt(8)
    float a = ACT_C * acc / (1.0f + expf(-acc));
    h[wl][lane] = a;
    __syncthreads();
    acc = 0.0f;
    #pragma unroll 8
    for (int k = 0; k < 64; ++k) acc += h[wl][k] * W2[k * 64 + lane];
    acc *= 0.125f;                             // 1/sqrt(64)
    a = ACT_C * acc / (1.0f + expf(-acc));
    __syncthreads();
    h[wl][lane] = a;
    __syncthreads();
    float m0 = 0.f, m1 = 0.f, m2 = 0.f, m3 = 0.f;
    #pragma unroll 4
    for (int k = 0; k < 64; ++k) {
        float hk = h[wl][k];
        const float* w = W3 + k * 256 + lane;
        m0 += hk * w[0];
        m1 += hk * w[64];
        m2 += hk * w[128];
        m3 += hk * w[192];
    }
    __half2 h01 = __floats2half2_rn(m0 * 0.125f, m1 * 0.125f);
    __half2 h23 = __floats2half2_rn(m2 * 0.125f, m3 * 0.125f);
    uint2 r;
    r.x = *(unsigned int*)&h01;
    r.y = *(unsigned int*)&h23;
    g_tbl[wid * 64 + lane] = r;
}

__device__ __forceinline__ void edge_math(uint2 q0, uint2 q1, uint2 nv, float f,
                                          float yx, float yy, float yz,
                                          float& accA, float& accB,
                                          float& aCx, float& aCy, float& aCz,
                                          float& aDx, float& aDy, float& aDz) {
    float2 a0 = h2f(q0.x);                     // (mA,mB) @ i
    float2 b0 = h2f(q0.y);                     // (mC,mD) @ i
    float2 a1 = h2f(q1.x);                     // (mA,mB) @ i+1
    float2 b1 = h2f(q1.y);                     // (mC,mD) @ i+1
    float2 p01 = h2f(nv.x);                    // (m0, vx)
    float2 p23 = h2f(nv.y);                    // (vy, vz)

    float mA = fmaf(f, a1.x - a0.x, a0.x);
    float mB = fmaf(f, a1.y - a0.y, a0.y);
    float mC = fmaf(f, b1.x - b0.x, b0.x);
    float mD = fmaf(f, b1.y - b0.y, b0.y);

    float m0u = p01.x, vx = p01.y, vy = p23.x, vzv = p23.y;
    float tp0 = fmaf(vx, yx, fmaf(vy, yy, vzv * yz));
    accA = fmaf(m0u, mA, accA);
    accB = fmaf(tp0, mB, accB);
    aCx = fmaf(mC, vx,  aCx);
    aCy = fmaf(mC, vy,  aCy);
    aCz = fmaf(mC, vzv, aCz);
    float cD = m0u * mD * S3;
    aDx = fmaf(cD, yx, aDx);
    aDy = fmaf(cD, yy, aDy);
    aDz = fmaf(cD, yz, aDz);
}

// 1024 blocks x 8 waves (8 waves/SIMD target); 32KB LDS table; wave-per-node grid-stride;
// 8-deep batched node-feature loads = 64 outstanding loads/SIMD at full occupancy.
__global__ __launch_bounds__(GATHER_THREADS, 8) void gather_kernel(float* __restrict__ out) {
    __shared__ uint2 tbl[TBL_ROWS * 64];       // 32768 B
    const int tid = threadIdx.x;
    for (int i = tid; i < TBL_ROWS * 64; i += GATHER_THREADS)
        tbl[i] = g_tbl[i];
    __syncthreads();

    const int u = tid & 63;
    const int w = tid >> 6;                              // 0..7
    const int nwaves = GATHER_BLOCKS * 8;                // 8192

    for (int n = (int)blockIdx.x * 8 + w; n < N_NODES; n += nwaves) {
        const int base = n << 6;
        int cnt = g_cnt[n];                              // issue...
        const float4 myrec = g_bkt[base + u];            // ...concurrently (always in-bounds;
                                                         // lanes >= cnt hold junk, never consumed)
        if (cnt > CAP) cnt = CAP;

        float accA = 0.f, accB = 0.f;
        float aCx = 0.f, aCy = 0.f, aCz = 0.f;
        float aDx = 0.f, aDy = 0.f, aDz = 0.f;

        for (int j = 0; j < cnt; j += 8) {
            uint2 nv[8];                                 // statically indexed only
            #pragma unroll
            for (int k = 0; k < 8; ++k) {                // 8 loads in flight; tail re-issues
                int jj = j + k; if (jj >= cnt) jj = cnt - 1;    // last edge's address (wave-uniform)
                unsigned int bits = __float_as_uint(__shfl(myrec.w, jj));
                nv[k] = g_nd2[(int)(bits >> 16) * 64 + u];
            }
            #pragma unroll
            for (int k = 0; k < 8; ++k) {
                int jj = j + k;
                if (jj < cnt) {                          // wave-uniform guard
                    float yx = __shfl(myrec.x, jj);
                    float yy = __shfl(myrec.y, jj);
                    float yz = __shfl(myrec.z, jj);
                    unsigned int bits = __float_as_uint(__shfl(myrec.w, jj));
                    int i = (int)((bits >> 9) & 127u);
                    float f = (float)(bits & 511u) * (1.0f / 512.0f);
                    edge_math(tbl[i * 64 + u], tbl[i * 64 + 64 + u], nv[k], f,
                              yx, yy, yz, accA, accB, aCx, aCy, aCz, aDx, aDy, aDz);
                }
            }
        }

        const float inv = 0.25f;                         // 1/sqrt(AVG_NEIGH)
        float* o = out + (size_t)n * 512;
        o[u]       = inv * accA;
        o[64 + u]  = inv * accB;
        o[128 + 3 * u + 0] = inv * aCx;
        o[128 + 3 * u + 1] = inv * aCy;
        o[128 + 3 * u + 2] = inv * aCz;
        o[320 + 3 * u + 0] = inv * aDx;
        o[320 + 3 * u + 1] = inv * aDy;
        o[320 + 3 * u + 2] = inv * aDz;
        if (u == 0) g_cnt[n] = 0;                        // self-clean for next call
    }
}

extern "C" void kernel_launch(void* const* d_in, const int* in_sizes, int n_in,
                              void* d_out, int out_size, void* d_ws, size_t ws_size,
                              hipStream_t stream) {
    const float* vectors      = (const float*)d_in[0];
    const float* node_scalars = (const float*)d_in[1];
    const float* node_vectors = (const float*)d_in[2];
    const int*   senders      = (const int*)d_in[3];
    const int*   receivers    = (const int*)d_in[4];
    const float* W1           = (const float*)d_in[5];
    const float* W2           = (const float*)d_in[6];
    const float* W3           = (const float*)d_in[7];
    float* out = (float*)d_out;

    prep_scatter<<<SCAT_BLOCKS + CONV_BLOCKS + TBL_BLOCKS, 256, 0, stream>>>(
        W1, W2, W3, node_scalars, node_vectors, vectors, senders, receivers);
    gather_kernel<<<GATHER_BLOCKS, GATHER_THREADS, 0, stream>>>(out);
    // out fully written per node (all 512 channels) -> no memset needed
}

// Round 12
// 44.705 us; speedup vs baseline: 1.0172x; 1.0172x over previous
//
#include <hip/hip_runtime.h>
#include <hip/hip_fp16.h>
#include <math.h>

#define N_NODES 10000
#define N_EDGES 160000
#define TBL_N 126               // intervals; 127 rows (absmax ~0.25 at this resolution; 63 gave 1.125)
#define TBL_ROWS 127
#define ACT_C 1.676518f         // 1/sqrt(E[silu(z)^2]), z~N(0,1)
#define CAP 64                  // bucket capacity per node (mean valid degree ~15.4; P(>64)~e^-40)
#define S3 1.7320508075688772f

#define SCAT_BLOCKS 625         // 160000 edges / 256
#define CONV_BLOCKS 2500        // 4 nodes per block (wave-per-node)
#define TBL_BLOCKS  32          // 128 waves >= 127 rows
#define GATHER_BLOCKS 2500      // 4 waves/block, 1 node/wave: exact cover of 10000 nodes

// mix table rows (global; 65KB, L2-resident in every XCD): lane u = half4 {mA,mB,mC,mD}
__device__ uint2  g_tbl[TBL_ROWS * 64];
// packed node features: lane u = half4 {m0, vx, vy, vz}
__device__ uint2  g_nd2[N_NODES * 64];
// counters: zero at module load (.bss); gather resets to zero at end of EVERY call
__device__ int    g_cnt[N_NODES];
// bucket record: {yhat_x, yhat_y, yhat_z, bits = sender<<16 | idx7<<9 | frac9}
__device__ float4 g_bkt[N_NODES * CAP];

__device__ __forceinline__ float2 h2f(unsigned int v) {
    __half2 h = *(__half2*)&v;
    return __half22float2(h);
}

// Fused prep+scatter: roles by blockIdx. No inter-role dependencies
// (scatter needs only g_cnt==0, guaranteed by previous gather / module load).
__global__ __launch_bounds__(256) void prep_scatter(
    const float* __restrict__ W1, const float* __restrict__ W2, const float* __restrict__ W3,
    const float* __restrict__ node_scalars, const float* __restrict__ node_vectors,
    const float* __restrict__ vectors, const int* __restrict__ senders,
    const int* __restrict__ receivers)
{
    const int bx = (int)blockIdx.x;
    const int tid = threadIdx.x;
    const int lane = tid & 63;
    const int wl = tid >> 6;

    if (bx < SCAT_BLOCKS) {                    // ---- scatter edges into receiver buckets ----
        int e = bx * 256 + tid;
        if (e < N_EDGES) {
            float vx = vectors[3 * e], vy = vectors[3 * e + 1], vz = vectors[3 * e + 2];
            float x2 = vx * vx + vy * vy + vz * vz;
            if (x2 < 1.0f) {                   // envelope==0 edges dropped
                float invx = rsqrtf(x2);
                float x = x2 * invx;
                float t = x * (float)TBL_N;    // t < 126 -> idx <= 125, rows i,i+1 <= 126
                int idx = (int)t;            if (idx > TBL_N - 1) idx = TBL_N - 1;
                int fr  = (int)((t - (float)idx) * 512.0f);  if (fr > 511) fr = 511;
                unsigned int bits = ((unsigned int)senders[e] << 16) |
                                    ((unsigned int)idx << 9) | (unsigned int)fr;
                int r = receivers[e];
                int slot = atomicAdd(&g_cnt[r], 1);
                if (slot < CAP)                // overflow clamp (never taken in practice)
                    g_bkt[(r << 6) + slot] =
                        make_float4(vx * invx, vy * invx, vz * invx, __uint_as_float(bits));
            }
        }
        return;
    }
    if (bx < SCAT_BLOCKS + CONV_BLOCKS) {      // ---- fp16 node-feature packing ----
        int n = (bx - SCAT_BLOCKS) * 4 + wl;   // exactly covers [0,10000)
        float m0 = node_scalars[n * 64 + lane];
        const float* p = node_vectors + n * 192 + 3 * lane;
        __half2 h01 = __floats2half2_rn(m0, p[0]);
        __half2 h23 = __floats2half2_rn(p[1], p[2]);
        uint2 r;
        r.x = *(unsigned int*)&h01;
        r.y = *(unsigned int*)&h23;
        g_nd2[n * 64 + lane] = r;
        return;
    }

    // ---- mix-table MLP: 32 blocks * 4 waves = 128 waves, one per row (127 rows) ----
    __shared__ float h[4][64];
    int wid = (bx - SCAT_BLOCKS - CONV_BLOCKS) * 4 + wl;          // 0..127
    if (wid > TBL_N) wid = TBL_N;              // duplicate last row (benign identical write)
    const float x = (float)wid * (1.0f / (float)TBL_N);
    float x2 = x * x, x3 = x2 * x, x6 = x3 * x3;
    float env = (x < 1.0f) ? (1.0f - 28.0f * x6 + 48.0f * x6 * x - 21.0f * x6 * x2) : 0.0f;
    const float pi = 3.14159265358979f;
    float radial[8];
    #pragma unroll
    for (int k = 1; k <= 8; ++k) {
        float b = (x == 0.0f) ? ((float)k * pi) : (sinf(pi * (float)k * x) / x);
        radial[k - 1] = 1.41421356237f * b * env;
    }
    float acc = 0.0f;
    #pragma unroll
    for (int k = 0; k < 8; ++k) acc += radial[k] * W1[k * 64 + lane];
    acc *= 0.35355339059f;                     // 1/sqrt(8)
    float a = ACT_C * acc / (1.0f + expf(-acc));
    h[wl][lane] = a;
    __syncthreads();
    acc = 0.0f;
    #pragma unroll 8
    for (int k = 0; k < 64; ++k) acc += h[wl][k] * W2[k * 64 + lane];
    acc *= 0.125f;                             // 1/sqrt(64)
    a = ACT_C * acc / (1.0f + expf(-acc));
    __syncthreads();
    h[wl][lane] = a;
    __syncthreads();
    float m0 = 0.f, m1 = 0.f, m2 = 0.f, m3 = 0.f;
    #pragma unroll 4
    for (int k = 0; k < 64; ++k) {
        float hk = h[wl][k];
        const float* w = W3 + k * 256 + lane;
        m0 += hk * w[0];
        m1 += hk * w[64];
        m2 += hk * w[128];
        m3 += hk * w[192];
    }
    __half2 h01 = __floats2half2_rn(m0 * 0.125f, m1 * 0.125f);
    __half2 h23 = __floats2half2_rn(m2 * 0.125f, m3 * 0.125f);
    uint2 r;
    r.x = *(unsigned int*)&h01;
    r.y = *(unsigned int*)&h23;
    g_tbl[wid * 64 + lane] = r;
}

__device__ __forceinline__ void edge_math(uint2 q0, uint2 q1, uint2 nv, float f,
                                          float yx, float yy, float yz,
                                          float& accA, float& accB,
                                          float& aCx, float& aCy, float& aCz,
                                          float& aDx, float& aDy, float& aDz) {
    float2 a0 = h2f(q0.x);                     // (mA,mB) @ i
    float2 b0 = h2f(q0.y);                     // (mC,mD) @ i
    float2 a1 = h2f(q1.x);                     // (mA,mB) @ i+1
    float2 b1 = h2f(q1.y);                     // (mC,mD) @ i+1
    float2 p01 = h2f(nv.x);                    // (m0, vx)
    float2 p23 = h2f(nv.y);                    // (vy, vz)

    float mA = fmaf(f, a1.x - a0.x, a0.x);
    float mB = fmaf(f, a1.y - a0.y, a0.y);
    float mC = fmaf(f, b1.x - b0.x, b0.x);
    float mD = fmaf(f, b1.y - b0.y, b0.y);

    float m0u = p01.x, vx = p01.y, vy = p23.x, vzv = p23.y;
    float tp0 = fmaf(vx, yx, fmaf(vy, yy, vzv * yz));
    accA = fmaf(m0u, mA, accA);
    accB = fmaf(tp0, mB, accB);
    aCx = fmaf(mC, vx,  aCx);
    aCy = fmaf(mC, vy,  aCy);
    aCz = fmaf(mC, vzv, aCz);
    float cD = m0u * mD * S3;
    aDx = fmaf(cD, yx, aDx);
    aDy = fmaf(cD, yy, aDy);
    aDz = fmaf(cD, yz, aDz);
}

// 2500 blocks x 4 waves, one node per wave (exact cover). Wave-uniform node id in SGPR;
// edge records via SCALAR loads (s_load_dwordx4, SMEM pipe, free broadcast) -- no LDS, no shfl.
__global__ __launch_bounds__(256) void gather_kernel(float* __restrict__ out) {
    const int u = threadIdx.x & 63;
    const int nn = __builtin_amdgcn_readfirstlane((int)blockIdx.x * 4 + (threadIdx.x >> 6));

    int cnt = __builtin_amdgcn_readfirstlane(g_cnt[nn]);  // scalar load + clamp
    if (cnt > CAP) cnt = CAP;
    const uint4* __restrict__ bkt = (const uint4*)(g_bkt + ((size_t)nn << 6));

    float accA = 0.f, accB = 0.f;
    float aCx = 0.f, aCy = 0.f, aCz = 0.f;
    float aDx = 0.f, aDy = 0.f, aDz = 0.f;

    int j = 0;
    for (; j + 4 <= cnt; j += 4) {
        uint2 q0[4], q1[4], nv[4];
        float yx[4], yy[4], yz[4], f[4];
        #pragma unroll
        for (int k = 0; k < 4; ++k) {
            uint4 r = bkt[j + k];              // wave-uniform -> s_load_dwordx4 (SGPRs)
            yx[k] = __uint_as_float(r.x);
            yy[k] = __uint_as_float(r.y);
            yz[k] = __uint_as_float(r.z);
            unsigned int bits = r.w;
            f[k] = (float)(bits & 511u) * (1.0f / 512.0f);
            int i  = (int)((bits >> 9) & 127u);
            int sv = (int)(bits >> 16);
            nv[k] = g_nd2[sv * 64 + u];        // 3 vector loads/edge, SGPR base + lane offset
            q0[k] = g_tbl[i * 64 + u];
            q1[k] = g_tbl[i * 64 + 64 + u];
        }
        #pragma unroll
        for (int k = 0; k < 4; ++k)
            edge_math(q0[k], q1[k], nv[k], f[k], yx[k], yy[k], yz[k],
                      accA, accB, aCx, aCy, aCz, aDx, aDy, aDz);
    }
    for (; j < cnt; ++j) {
        uint4 r = bkt[j];
        float yx = __uint_as_float(r.x);
        float yy = __uint_as_float(r.y);
        float yz = __uint_as_float(r.z);
        unsigned int bits = r.w;
        float f = (float)(bits & 511u) * (1.0f / 512.0f);
        int i  = (int)((bits >> 9) & 127u);
        int sv = (int)(bits >> 16);
        edge_math(g_tbl[i * 64 + u], g_tbl[i * 64 + 64 + u], g_nd2[sv * 64 + u], f,
                  yx, yy, yz, accA, accB, aCx, aCy, aCz, aDx, aDy, aDz);
    }

    const float inv = 0.25f;                   // 1/sqrt(AVG_NEIGH)
    float* o = out + (size_t)nn * 512;
    o[u]       = inv * accA;
    o[64 + u]  = inv * accB;
    o[128 + 3 * u + 0] = inv * aCx;
    o[128 + 3 * u + 1] = inv * aCy;
    o[128 + 3 * u + 2] = inv * aCz;
    o[320 + 3 * u + 0] = inv * aDx;
    o[320 + 3 * u + 1] = inv * aDy;
    o[320 + 3 * u + 2] = inv * aDz;
    if (u == 0) g_cnt[nn] = 0;                 // self-clean for next call
}

extern "C" void kernel_launch(void* const* d_in, const int* in_sizes, int n_in,
                              void* d_out, int out_size, void* d_ws, size_t ws_size,
                              hipStream_t stream) {
    const float* vectors      = (const float*)d_in[0];
    const float* node_scalars = (const float*)d_in[1];
    const float* node_vectors = (const float*)d_in[2];
    const int*   senders      = (const int*)d_in[3];
    const int*   receivers    = (const int*)d_in[4];
    const float* W1           = (const float*)d_in[5];
    const float* W2           = (const float*)d_in[6];
    const float* W3           = (const float*)d_in[7];
    float* out = (float*)d_out;

    prep_scatter<<<SCAT_BLOCKS + CONV_BLOCKS + TBL_BLOCKS, 256, 0, stream>>>(
        W1, W2, W3, node_scalars, node_vectors, vectors, senders, receivers);
    gather_kernel<<<GATHER_BLOCKS, 256, 0, stream>>>(out);
    // out fully written per node (all 512 channels) -> no memset needed
}

// Round 13
// 43.332 us; speedup vs baseline: 1.0495x; 1.0317x over previous
//
#include <hip/hip_runtime.h>
#include <hip/hip_fp16.h>
#include <math.h>

#define N_NODES 10000
#define N_EDGES 160000
#define TBL_N 126               // intervals; 127 rows (lerp err ~3e-4; TBL_N=63 gave absmax 1.125 -> keep 126)
#define ACT_C 1.676518f         // 1/sqrt(E[silu(z)^2]), z~N(0,1)
#define CAP 64                  // bucket capacity per node (mean valid degree ~15.4; P(>64)~e^-40)
#define S3 1.7320508075688772f

#define TBL_BLOCKS  32          // 128 waves >= 127 rows -- FIRST so the serial MLP starts at t=0
#define SCAT_BLOCKS 625         // 160000 edges / 256
#define CONV_BLOCKS 2500        // 4 nodes per block (wave-per-node)
#define GATHER_BLOCKS 2500      // 4 waves/block, 1 node/wave: exact cover of 10000 nodes

// pair-row table: slot i (lane u) = {(mA,mB)@i, (mC,mD)@i, (mA,mB)@i+1, (mC,mD)@i+1}; ONE 16B load/edge
__device__ uint4  g_tblp[TBL_N * 64];
// packed node features: lane u = half4 {m0, vx, vy, vz}
__device__ uint2  g_nd2[N_NODES * 64];
// counters: zero at module load (.bss); gather resets to zero at end of EVERY call
__device__ int    g_cnt[N_NODES];
// bucket record: {yhat_x, yhat_y, yhat_z, bits = sender<<16 | idx7<<9 | frac9}
__device__ float4 g_bkt[N_NODES * CAP];

__device__ __forceinline__ float2 h2f(unsigned int v) {
    __half2 h = *(__half2*)&v;
    return __half22float2(h);
}
__device__ __forceinline__ __half2 u2h(unsigned int v) { return *(__half2*)&v; }

// Fused prep+scatter: roles by blockIdx (MLP first -> its serial tail overlaps the other roles).
// No inter-role dependencies (scatter needs only g_cnt==0, guaranteed by previous gather).
__global__ __launch_bounds__(256) void prep_scatter(
    const float* __restrict__ W1, const float* __restrict__ W2, const float* __restrict__ W3,
    const float* __restrict__ node_scalars, const float* __restrict__ node_vectors,
    const float* __restrict__ vectors, const int* __restrict__ senders,
    const int* __restrict__ receivers)
{
    const int bx = (int)blockIdx.x;
    const int tid = threadIdx.x;
    const int lane = tid & 63;
    const int wl = tid >> 6;

    if (bx < TBL_BLOCKS) {
        // ---- mix-table MLP: 32 blocks * 4 waves = 128 waves, one per row (127 rows) ----
        __shared__ float h[4][64];
        int wid = bx * 4 + wl;                 // 0..127
        if (wid > TBL_N) wid = TBL_N;          // duplicate last row (benign identical write)
        const float x = (float)wid * (1.0f / (float)TBL_N);
        float x2 = x * x, x3 = x2 * x, x6 = x3 * x3;
        float env = (x < 1.0f) ? (1.0f - 28.0f * x6 + 48.0f * x6 * x - 21.0f * x6 * x2) : 0.0f;
        const float pi = 3.14159265358979f;
        float radial[8];
        #pragma unroll
        for (int k = 1; k <= 8; ++k) {
            float b = (x == 0.0f) ? ((float)k * pi) : (sinf(pi * (float)k * x) / x);
            radial[k - 1] = 1.41421356237f * b * env;
        }
        float acc = 0.0f;
        #pragma unroll
        for (int k = 0; k < 8; ++k) acc += radial[k] * W1[k * 64 + lane];
        acc *= 0.35355339059f;                 // 1/sqrt(8)
        float a = ACT_C * acc / (1.0f + expf(-acc));
        h[wl][lane] = a;
        __syncthreads();
        acc = 0.0f;
        #pragma unroll 8
        for (int k = 0; k < 64; ++k) acc += h[wl][k] * W2[k * 64 + lane];
        acc *= 0.125f;                         // 1/sqrt(64)
        a = ACT_C * acc / (1.0f + expf(-acc));
        __syncthreads();
        h[wl][lane] = a;
        __syncthreads();
        float m0 = 0.f, m1 = 0.f, m2 = 0.f, m3 = 0.f;
        #pragma unroll 4
        for (int k = 0; k < 64; ++k) {
            float hk = h[wl][k];
            const float* w = W3 + k * 256 + lane;
            m0 += hk * w[0];
            m1 += hk * w[64];
            m2 += hk * w[128];
            m3 += hk * w[192];
        }
        __half2 h01 = __floats2half2_rn(m0 * 0.125f, m1 * 0.125f);
        __half2 h23 = __floats2half2_rn(m2 * 0.125f, m3 * 0.125f);
        uint2 r;
        r.x = *(unsigned int*)&h01;
        r.y = *(unsigned int*)&h23;
        // row wid = FIRST half of pair-slot wid, SECOND half of pair-slot wid-1
        if (wid < TBL_N) *(uint2*)&g_tblp[wid * 64 + lane] = r;
        if (wid >= 1)    *(uint2*)((char*)&g_tblp[(wid - 1) * 64 + lane] + 8) = r;
        return;
    }
    if (bx < TBL_BLOCKS + SCAT_BLOCKS) {       // ---- scatter edges into receiver buckets ----
        int e = (bx - TBL_BLOCKS) * 256 + tid;
        if (e < N_EDGES) {
            float vx = vectors[3 * e], vy = vectors[3 * e + 1], vz = vectors[3 * e + 2];
            float x2 = vx * vx + vy * vy + vz * vz;
            if (x2 < 1.0f) {                   // envelope==0 edges dropped
                float invx = rsqrtf(x2);
                float x = x2 * invx;
                float t = x * (float)TBL_N;    // t < 126 -> idx <= 125
                int idx = (int)t;            if (idx > TBL_N - 1) idx = TBL_N - 1;
                int fr  = (int)((t - (float)idx) * 512.0f);  if (fr > 511) fr = 511;
                unsigned int bits = ((unsigned int)senders[e] << 16) |
                                    ((unsigned int)idx << 9) | (unsigned int)fr;
                int r = receivers[e];
                int slot = atomicAdd(&g_cnt[r], 1);
                if (slot < CAP)                // overflow clamp (never taken in practice)
                    g_bkt[(r << 6) + slot] =
                        make_float4(vx * invx, vy * invx, vz * invx, __uint_as_float(bits));
            }
        }
        return;
    }
    // ---- fp16 node-feature packing ----
    {
        int n = (bx - TBL_BLOCKS - SCAT_BLOCKS) * 4 + wl;   // exactly covers [0,10000)
        float m0 = node_scalars[n * 64 + lane];
        const float* p = node_vectors + n * 192 + 3 * lane;
        __half2 h01 = __floats2half2_rn(m0, p[0]);
        __half2 h23 = __floats2half2_rn(p[1], p[2]);
        uint2 r;
        r.x = *(unsigned int*)&h01;
        r.y = *(unsigned int*)&h23;
        g_nd2[n * 64 + lane] = r;
    }
}

__device__ __forceinline__ void edge_math(uint4 q, uint2 nv, __half2 f2,
                                          float yx, float yy, float yz,
                                          float& accA, float& accB,
                                          float& aCx, float& aCy, float& aCz,
                                          float& aDx, float& aDy, float& aDz) {
    // packed-half2 lerp: 2x hsub2 + 2x hfma2 replace 8 f32 sub/fma + 8 cvts
    __half2 a0 = u2h(q.x), b0 = u2h(q.y), a1 = u2h(q.z), b1 = u2h(q.w);
    __half2 mAB = __hfma2(f2, __hsub2(a1, a0), a0);
    __half2 mCD = __hfma2(f2, __hsub2(b1, b0), b0);
    float mA = __low2float(mAB), mB = __high2float(mAB);
    float mC = __low2float(mCD), mD = __high2float(mCD);

    float2 p01 = h2f(nv.x);                    // (m0, vx)
    float2 p23 = h2f(nv.y);                    // (vy, vz)
    float m0u = p01.x, vx = p01.y, vy = p23.x, vzv = p23.y;
    float tp0 = fmaf(vx, yx, fmaf(vy, yy, vzv * yz));
    accA = fmaf(m0u, mA, accA);
    accB = fmaf(tp0, mB, accB);
    aCx = fmaf(mC, vx,  aCx);
    aCy = fmaf(mC, vy,  aCy);
    aCz = fmaf(mC, vzv, aCz);
    float cD = m0u * mD * S3;
    aDx = fmaf(cD, yx, aDx);
    aDy = fmaf(cD, yy, aDy);
    aDz = fmaf(cD, yz, aDz);
}

// 2500 blocks x 4 waves, one node per wave. Wave-uniform records via SCALAR loads;
// per edge: ONE uint4 table load (pair-row) + ONE uint2 feature load. 4-deep pipeline.
__global__ __launch_bounds__(256) void gather_kernel(float* __restrict__ out) {
    const int u = threadIdx.x & 63;
    const int nn = __builtin_amdgcn_readfirstlane((int)blockIdx.x * 4 + (threadIdx.x >> 6));

    int cnt = __builtin_amdgcn_readfirstlane(g_cnt[nn]);
    if (cnt > CAP) cnt = CAP;
    const uint4* __restrict__ bkt = (const uint4*)(g_bkt + ((size_t)nn << 6));

    float accA = 0.f, accB = 0.f;
    float aCx = 0.f, aCy = 0.f, aCz = 0.f;
    float aDx = 0.f, aDy = 0.f, aDz = 0.f;

    int j = 0;
    for (; j + 4 <= cnt; j += 4) {
        uint4 q[4]; uint2 nv[4];
        float yx[4], yy[4], yz[4]; __half2 f2[4];
        #pragma unroll
        for (int k = 0; k < 4; ++k) {
            uint4 r = bkt[j + k];              // wave-uniform -> scalar load
            yx[k] = __uint_as_float(r.x);
            yy[k] = __uint_as_float(r.y);
            yz[k] = __uint_as_float(r.z);
            unsigned int bits = r.w;
            f2[k] = __float2half2_rn((float)(bits & 511u) * (1.0f / 512.0f));
            int i  = (int)((bits >> 9) & 127u);
            int sv = (int)(bits >> 16);
            q[k]  = g_tblp[i * 64 + u];        // ONE 16B load: both lerp rows
            nv[k] = g_nd2[sv * 64 + u];        // ONE 8B load: {m0,vx,vy,vz}
        }
        #pragma unroll
        for (int k = 0; k < 4; ++k)
            edge_math(q[k], nv[k], f2[k], yx[k], yy[k], yz[k],
                      accA, accB, aCx, aCy, aCz, aDx, aDy, aDz);
    }
    for (; j < cnt; ++j) {
        uint4 r = bkt[j];
        float yx = __uint_as_float(r.x);
        float yy = __uint_as_float(r.y);
        float yz = __uint_as_float(r.z);
        unsigned int bits = r.w;
        __half2 f2 = __float2half2_rn((float)(bits & 511u) * (1.0f / 512.0f));
        int i  = (int)((bits >> 9) & 127u);
        int sv = (int)(bits >> 16);
        edge_math(g_tblp[i * 64 + u], g_nd2[sv * 64 + u], f2,
                  yx, yy, yz, accA, accB, aCx, aCy, aCz, aDx, aDy, aDz);
    }

    const float inv = 0.25f;                   // 1/sqrt(AVG_NEIGH)
    float* o = out + (size_t)nn * 512;
    o[u]       = inv * accA;
    o[64 + u]  = inv * accB;
    o[128 + 3 * u + 0] = inv * aCx;
    o[128 + 3 * u + 1] = inv * aCy;
    o[128 + 3 * u + 2] = inv * aCz;
    o[320 + 3 * u + 0] = inv * aDx;
    o[320 + 3 * u + 1] = inv * aDy;
    o[320 + 3 * u + 2] = inv * aDz;
    if (u == 0) g_cnt[nn] = 0;                 // self-clean for next call
}

extern "C" void kernel_launch(void* const* d_in, const int* in_sizes, int n_in,
                              void* d_out, int out_size, void* d_ws, size_t ws_size,
                              hipStream_t stream) {
    const float* vectors      = (const float*)d_in[0];
    const float* node_scalars = (const float*)d_in[1];
    const float* node_vectors = (const float*)d_in[2];
    const int*   senders      = (const int*)d_in[3];
    const int*   receivers    = (const int*)d_in[4];
    const float* W1           = (const float*)d_in[5];
    const float* W2           = (const float*)d_in[6];
    const float* W3           = (const float*)d_in[7];
    float* out = (float*)d_out;

    prep_scatter<<<TBL_BLOCKS + SCAT_BLOCKS + CONV_BLOCKS, 256, 0, stream>>>(
        W1, W2, W3, node_scalars, node_vectors, vectors, senders, receivers);
    gather_kernel<<<GATHER_BLOCKS, 256, 0, stream>>>(out);
    // out fully written per node (all 512 channels) -> no memset needed
}